// Round 2
// baseline (2028.488 us; speedup 1.0000x reference)
//
#include <hip/hip_runtime.h>

// CapsuleLayer dynamic routing on MI355X — round 2.
// x: [128, 2048, 8] f32, W: [2048, 32, 8, 16] f32, out v: [128, 32, 16] f32.
// 3 recompute passes (never materialize u_hat), R=4 b-register-blocking,
// swizzled LDS W staging via global_load_lds(16B), no-max softmax.

constexpr int NC = 2048;   // in_caps
constexpr int OC = 32;     // out_caps
constexpr int OD = 16;     // out_dim

typedef const __attribute__((address_space(1))) void* gas1_t;
typedef __attribute__((address_space(3))) void* las3_t;

__device__ __forceinline__ void gld16(const void* g, void* l) {
    __builtin_amdgcn_global_load_lds((gas1_t)g, (las3_t)l, 16, 0, 0);
}

// Pass kernel.
// grid = 1024 blocks: nsup(128) x bt(8). block = 256 threads = 4 waves.
// Block: b in [bt*16, bt*16+16), n in [nsup*16, nsup*16+16) via 4 staged chunks of 4 n.
// Wave w owns b-group b0 = bt*16 + w*4 .. +3 (R=4).
// Lane: o = lane&31 (one out-cap, all 16 d), n-half h = lane>>5.
// LDS W layout (per chunk): unit index np*1024 + o*32 + ((i*4+q) ^ (o&7))  [float4 units]
//   -> the 32-lane column read at fixed (i,q) spreads over all 8 bank groups.
template<bool FIRST>
__global__ __launch_bounds__(256, 2)
void caps_pass(const float* __restrict__ xg, const float* __restrict__ Wg,
               const float* __restrict__ vin, float* __restrict__ sout)
{
    __shared__ float4 Wl[4096];   // 64 KB: 4 n x 1024 float4 (swizzled)
    __shared__ float4 xl[128];    // 2 KB: [np(4)][bp(16)][k(2)]

    const int tid  = threadIdx.x;
    const int nsup = blockIdx.x >> 3;   // 0..127
    const int bt   = blockIdx.x & 7;    // 0..7
    const int w    = tid >> 6;          // wave 0..3
    const int lane = tid & 63;
    const int o    = lane & 31;
    const int h    = lane >> 5;
    const int b0   = bt * 16 + w * 4;
    const int sw   = o & 7;

    const float4* Wg4 = (const float4*)Wg;
    const float4* xg4 = (const float4*)xg;

    float4 acc[4][4];   // [r][q]  s-partial for b0+r, o, d=4q..4q+3
#pragma unroll
    for (int r = 0; r < 4; ++r)
#pragma unroll
        for (int q = 0; q < 4; ++q) acc[r][q] = make_float4(0.f, 0.f, 0.f, 0.f);

    float4 vr[4][4];    // routing vector v[b0+r][o][:]
    if (!FIRST) {
        const float4* v4 = (const float4*)vin;
#pragma unroll
        for (int r = 0; r < 4; ++r)
#pragma unroll
            for (int q = 0; q < 4; ++q)
                vr[r][q] = v4[(size_t)(b0 + r) * 128 + o * 4 + q];
    }

#pragma unroll 1
    for (int it = 0; it < 4; ++it) {
        const int nbase = nsup * 16 + it * 4;
        __syncthreads();   // previous chunk's compute done before overwrite

        // ---- stage W chunk: 4096 float4, 16 per thread, pre-swizzled source ----
#pragma unroll
        for (int j = 0; j < 16; ++j) {
            const int L  = tid + 256 * j;        // LDS float4 unit (lane-linear)
            const int np = L >> 10;
            const int oo = (L >> 5) & 31;
            const int cc = L & 31;
            const size_t gidx = (size_t)(nbase + np) * 1024 + oo * 32 + (cc ^ (oo & 7));
            gld16(&Wg4[gidx], &Wl[L]);
        }
        // ---- stage x chunk: [np][bp][k] ----
        if (tid < 128) {
            const int np = tid >> 5, bp = (tid >> 1) & 15, k = tid & 1;
            xl[tid] = xg4[(size_t)(bt * 16 + bp) * 4096 + (size_t)(nbase + np) * 2 + k];
        }
        __syncthreads();   // compiler drains vmcnt before barrier

        // ---- compute: 2 pairs, lane handles n = nbase + p*2 + h ----
#pragma unroll
        for (int p = 0; p < 2; ++p) {
            const int np = p * 2 + h;

            float xr[4][8];
#pragma unroll
            for (int r = 0; r < 4; ++r) {
                const float4 xa = xl[np * 32 + (w * 4 + r) * 2 + 0];
                const float4 xb = xl[np * 32 + (w * 4 + r) * 2 + 1];
                xr[r][0] = xa.x; xr[r][1] = xa.y; xr[r][2] = xa.z; xr[r][3] = xa.w;
                xr[r][4] = xb.x; xr[r][5] = xb.y; xr[r][6] = xb.z; xr[r][7] = xb.w;
            }

            const float4* wrow = &Wl[np * 1024 + o * 32];

            if (FIRST) {
                // uniform c: accumulate u directly into acc (scaled 1/32 at store)
#pragma unroll
                for (int i = 0; i < 8; ++i)
#pragma unroll
                    for (int q = 0; q < 4; ++q) {
                        const float4 wv = wrow[(i * 4 + q) ^ sw];
#pragma unroll
                        for (int r = 0; r < 4; ++r) {
                            acc[r][q].x = fmaf(xr[r][i], wv.x, acc[r][q].x);
                            acc[r][q].y = fmaf(xr[r][i], wv.y, acc[r][q].y);
                            acc[r][q].z = fmaf(xr[r][i], wv.z, acc[r][q].z);
                            acc[r][q].w = fmaf(xr[r][i], wv.w, acc[r][q].w);
                        }
                    }
            } else {
                float4 u[4][4];
#pragma unroll
                for (int r = 0; r < 4; ++r)
#pragma unroll
                    for (int q = 0; q < 4; ++q) u[r][q] = make_float4(0.f, 0.f, 0.f, 0.f);

#pragma unroll
                for (int i = 0; i < 8; ++i)
#pragma unroll
                    for (int q = 0; q < 4; ++q) {
                        const float4 wv = wrow[(i * 4 + q) ^ sw];
#pragma unroll
                        for (int r = 0; r < 4; ++r) {
                            u[r][q].x = fmaf(xr[r][i], wv.x, u[r][q].x);
                            u[r][q].y = fmaf(xr[r][i], wv.y, u[r][q].y);
                            u[r][q].z = fmaf(xr[r][i], wv.z, u[r][q].z);
                            u[r][q].w = fmaf(xr[r][i], wv.w, u[r][q].w);
                        }
                    }

#pragma unroll
                for (int r = 0; r < 4; ++r) {
                    // logit t = dot(u, v)  (in-lane, full d)
                    float t = 0.f;
#pragma unroll
                    for (int q = 0; q < 4; ++q) {
                        t = fmaf(u[r][q].x, vr[r][q].x, t);
                        t = fmaf(u[r][q].y, vr[r][q].y, t);
                        t = fmaf(u[r][q].z, vr[r][q].z, t);
                        t = fmaf(u[r][q].w, vr[r][q].w, t);
                    }
                    // softmax over o = 32 lanes of this half; |t| <~ 75 so exp is
                    // fp32-safe without max subtraction (e^88 overflows, Z<=32e^75).
                    const float e = __expf(t);
                    float Z = e;
                    Z += __shfl_xor(Z, 1);
                    Z += __shfl_xor(Z, 2);
                    Z += __shfl_xor(Z, 4);
                    Z += __shfl_xor(Z, 8);
                    Z += __shfl_xor(Z, 16);
                    const float c = e / Z;
#pragma unroll
                    for (int q = 0; q < 4; ++q) {
                        acc[r][q].x = fmaf(c, u[r][q].x, acc[r][q].x);
                        acc[r][q].y = fmaf(c, u[r][q].y, acc[r][q].y);
                        acc[r][q].z = fmaf(c, u[r][q].z, acc[r][q].z);
                        acc[r][q].w = fmaf(c, u[r][q].w, acc[r][q].w);
                    }
                }
            }
        }
    }

    // combine the two n-halves (lane ^ 32 holds same (b,o,d))
#pragma unroll
    for (int r = 0; r < 4; ++r)
#pragma unroll
        for (int q = 0; q < 4; ++q) {
            acc[r][q].x += __shfl_xor(acc[r][q].x, 32);
            acc[r][q].y += __shfl_xor(acc[r][q].y, 32);
            acc[r][q].z += __shfl_xor(acc[r][q].z, 32);
            acc[r][q].w += __shfl_xor(acc[r][q].w, 32);
        }

    if (h == 0) {
        const float sc = FIRST ? (1.0f / 32.0f) : 1.0f;
#pragma unroll
        for (int r = 0; r < 4; ++r) {
            float* sb = sout + (size_t)(b0 + r) * (OC * OD) + o * OD;
#pragma unroll
            for (int q = 0; q < 4; ++q) {
                atomicAdd(sb + q * 4 + 0, acc[r][q].x * sc);
                atomicAdd(sb + q * 4 + 1, acc[r][q].y * sc);
                atomicAdd(sb + q * 4 + 2, acc[r][q].z * sc);
                atomicAdd(sb + q * 4 + 3, acc[r][q].w * sc);
            }
        }
    }
}

// squash over d for each (b,o) row; optionally add vprev (to build v0+v1).
__global__ void squash_k(const float* __restrict__ s, const float* __restrict__ vprev,
                         float* __restrict__ vout)
{
    const int row = blockIdx.x * blockDim.x + threadIdx.x;   // 0..4095 = b*32+o
    if (row >= 128 * 32) return;
    const float4* s4 = (const float4*)s;
    float4 t[4];
    float sq = 0.f;
#pragma unroll
    for (int q = 0; q < 4; ++q) {
        t[q] = s4[row * 4 + q];
        sq += t[q].x * t[q].x + t[q].y * t[q].y + t[q].z * t[q].z + t[q].w * t[q].w;
    }
    const float f = sq / ((1.0f + sq) * sqrtf(sq + 1e-8f));
    float4* o4 = (float4*)vout;
    if (vprev) {
        const float4* p4 = (const float4*)vprev;
#pragma unroll
        for (int q = 0; q < 4; ++q) {
            float4 p = p4[row * 4 + q];
            float4 r;
            r.x = fmaf(t[q].x, f, p.x);
            r.y = fmaf(t[q].y, f, p.y);
            r.z = fmaf(t[q].z, f, p.z);
            r.w = fmaf(t[q].w, f, p.w);
            o4[row * 4 + q] = r;
        }
    } else {
#pragma unroll
        for (int q = 0; q < 4; ++q) {
            float4 r;
            r.x = t[q].x * f; r.y = t[q].y * f; r.z = t[q].z * f; r.w = t[q].w * f;
            o4[row * 4 + q] = r;
        }
    }
}

extern "C" void kernel_launch(void* const* d_in, const int* in_sizes, int n_in,
                              void* d_out, int out_size, void* d_ws, size_t ws_size,
                              hipStream_t stream)
{
    const float* x = (const float*)d_in[0];
    const float* W = (const float*)d_in[1];
    float* s  = (float*)d_ws;            // 65536 f32
    float* v0 = s + 65536;               // 65536 f32
    float* vs = v0 + 65536;              // 65536 f32 (v0 + v1)
    float* out = (float*)d_out;

    const size_t sbytes = (size_t)65536 * sizeof(float);

    // iter 0: uniform coupling 1/32
    hipMemsetAsync(s, 0, sbytes, stream);
    caps_pass<true><<<dim3(1024), dim3(256), 0, stream>>>(x, W, nullptr, s);
    squash_k<<<dim3(16), dim3(256), 0, stream>>>(s, nullptr, v0);

    // iter 1: logits = dot(u_hat, v0)
    hipMemsetAsync(s, 0, sbytes, stream);
    caps_pass<false><<<dim3(1024), dim3(256), 0, stream>>>(x, W, v0, s);
    squash_k<<<dim3(16), dim3(256), 0, stream>>>(s, v0, vs);   // vs = v0 + v1

    // iter 2: logits = dot(u_hat, v0) + dot(u_hat, v1) = dot(u_hat, vs)
    hipMemsetAsync(s, 0, sbytes, stream);
    caps_pass<false><<<dim3(1024), dim3(256), 0, stream>>>(x, W, vs, s);
    squash_k<<<dim3(16), dim3(256), 0, stream>>>(s, nullptr, out);
}

// Round 3
// 583.060 us; speedup vs baseline: 3.4790x; 3.4790x over previous
//
#include <hip/hip_runtime.h>

// CapsuleLayer dynamic routing on MI355X — round 3.
// x: [128, 2048, 8] f32, W: [2048, 32, 8, 16] f32, out v: [128, 32, 16] f32.
// Fixes round-2 spill: d-split across wave halves (state = 96 VGPR) and x via
// scalar loads (SGPRs). R=4 b-reuse of each LDS W read. 3 recompute passes.

constexpr int NC = 2048;   // in_caps
constexpr int OC = 32;     // out_caps
constexpr int OD = 16;     // out_dim

typedef const __attribute__((address_space(1))) void* gas1_t;
typedef __attribute__((address_space(3))) void* las3_t;

__device__ __forceinline__ void gld16(const void* g, void* l) {
    __builtin_amdgcn_global_load_lds((gas1_t)g, (las3_t)l, 16, 0, 0);
}

// grid = 512 blocks: nsup(64) x bt(8), XCD-swizzled so the 8 bt-blocks sharing
// one W-slice sit on one XCD (W slice 512KB x 8 slices = 4MB = one L2).
// block = 256 threads = 4 waves. Block covers b in [bt*16,+16), n in [nsup*32,+32)
// via 8 chunks of 4 n. Wave w owns b0 = bt*16 + w*4 (R=4).
// Lane: o = lane&31, d-half h = lane>>5 (d = h*8 + 0..7).
// LDS W (per chunk): float4 unit np*1024 + o*32 + (c ^ (o&7))  [pre-swizzled src,
// linear dest for global_load_lds; read with same XOR -> conflict-free column read].
template<bool FIRST>
__global__ __launch_bounds__(256)
__attribute__((amdgpu_waves_per_eu(2, 2)))
void caps_pass(const float* __restrict__ xg, const float* __restrict__ Wg,
               const float* __restrict__ vin, float* __restrict__ sout)
{
    __shared__ float4 Wl[4096];   // 64 KB: 4 n x (32 o x 32 c) float4, swizzled

    const int tid  = threadIdx.x;
    const int bid  = blockIdx.x;
    // forward map: bid = (nsup&7) | (bt<<3) | ((nsup>>3)<<6)
    const int nsup = (bid & 7) | ((bid >> 6) << 3);   // 0..63
    const int bt   = (bid >> 3) & 7;                  // 0..7
    const int w    = __builtin_amdgcn_readfirstlane(tid >> 6);  // uniform wave id
    const int lane = tid & 63;
    const int o    = lane & 31;
    const int h    = lane >> 5;
    const int sw   = o & 7;
    const int b0   = bt * 16 + w * 4;

    const float4* Wg4 = (const float4*)Wg;

    float4 acc[4][2];   // [r][qq]: s-partial for b0+r, o, d = h*8 + qq*4 ..+3
#pragma unroll
    for (int r = 0; r < 4; ++r)
#pragma unroll
        for (int qq = 0; qq < 2; ++qq) acc[r][qq] = make_float4(0.f, 0.f, 0.f, 0.f);

    float4 vr[4][2];    // v[b0+r][o][h-half]
    if (!FIRST) {
        const float4* v4 = (const float4*)vin;
#pragma unroll
        for (int r = 0; r < 4; ++r)
#pragma unroll
            for (int qq = 0; qq < 2; ++qq)
                vr[r][qq] = v4[(size_t)(b0 + r) * 128 + o * 4 + h * 2 + qq];
    }

#pragma unroll 1
    for (int it = 0; it < 8; ++it) {
        const int nbase = nsup * 32 + it * 4;
        __syncthreads();   // previous chunk's compute done before overwrite
        // ---- stage W chunk: 4096 float4, 16 per thread, pre-swizzled source ----
#pragma unroll
        for (int j = 0; j < 16; ++j) {
            const int L  = tid + 256 * j;        // lane-linear LDS unit
            const int np = L >> 10;
            const int oo = (L >> 5) & 31;
            const int cc = L & 31;
            gld16(&Wg4[(size_t)(nbase + np) * 1024 + oo * 32 + (cc ^ (oo & 7))], &Wl[L]);
        }
        __syncthreads();   // drains vmcnt; staged data visible

#pragma unroll
        for (int np = 0; np < 4; ++np) {
            const int n = nbase + np;

            // x is wave-uniform -> scalar loads into SGPRs (no VGPR/LDS cost)
            float xs[4][8];
#pragma unroll
            for (int r = 0; r < 4; ++r) {
                const float* xp = xg + ((size_t)(b0 + r) * NC + n) * 8;
#pragma unroll
                for (int i = 0; i < 8; ++i) xs[r][i] = xp[i];
            }

            const float4* wrow = &Wl[np * 1024 + o * 32];

            float4 u[4][2];
#pragma unroll
            for (int r = 0; r < 4; ++r)
#pragma unroll
                for (int qq = 0; qq < 2; ++qq) u[r][qq] = make_float4(0.f, 0.f, 0.f, 0.f);

#pragma unroll
            for (int i = 0; i < 8; ++i)
#pragma unroll
                for (int qq = 0; qq < 2; ++qq) {
                    const float4 wv = wrow[(i * 4 + h * 2 + qq) ^ sw];
#pragma unroll
                    for (int r = 0; r < 4; ++r) {
                        u[r][qq].x = fmaf(xs[r][i], wv.x, u[r][qq].x);
                        u[r][qq].y = fmaf(xs[r][i], wv.y, u[r][qq].y);
                        u[r][qq].z = fmaf(xs[r][i], wv.z, u[r][qq].z);
                        u[r][qq].w = fmaf(xs[r][i], wv.w, u[r][qq].w);
                    }
                }

            if (FIRST) {
#pragma unroll
                for (int r = 0; r < 4; ++r)
#pragma unroll
                    for (int qq = 0; qq < 2; ++qq) {
                        acc[r][qq].x += u[r][qq].x;
                        acc[r][qq].y += u[r][qq].y;
                        acc[r][qq].z += u[r][qq].z;
                        acc[r][qq].w += u[r][qq].w;
                    }
            } else {
#pragma unroll
                for (int r = 0; r < 4; ++r) {
                    // half-dot over this lane's 8 d's, combine across halves
                    float tp = 0.f;
#pragma unroll
                    for (int qq = 0; qq < 2; ++qq) {
                        tp = fmaf(u[r][qq].x, vr[r][qq].x, tp);
                        tp = fmaf(u[r][qq].y, vr[r][qq].y, tp);
                        tp = fmaf(u[r][qq].z, vr[r][qq].z, tp);
                        tp = fmaf(u[r][qq].w, vr[r][qq].w, tp);
                    }
                    const float t = tp + __shfl_xor(tp, 32);
                    // softmax over the 32 o-lanes (both halves identical).
                    // |t| <= ~60 -> exp is fp32-safe without max subtraction.
                    const float e = __expf(t);
                    float Z = e;
                    Z += __shfl_xor(Z, 1);
                    Z += __shfl_xor(Z, 2);
                    Z += __shfl_xor(Z, 4);
                    Z += __shfl_xor(Z, 8);
                    Z += __shfl_xor(Z, 16);
                    const float c = e / Z;
#pragma unroll
                    for (int qq = 0; qq < 2; ++qq) {
                        acc[r][qq].x = fmaf(c, u[r][qq].x, acc[r][qq].x);
                        acc[r][qq].y = fmaf(c, u[r][qq].y, acc[r][qq].y);
                        acc[r][qq].z = fmaf(c, u[r][qq].z, acc[r][qq].z);
                        acc[r][qq].w = fmaf(c, u[r][qq].w, acc[r][qq].w);
                    }
                }
            }
        }
    }

    // flush: every lane owns (b0+r, o, d-half) exclusively within this block
    const float sc = FIRST ? (1.0f / 32.0f) : 1.0f;
#pragma unroll
    for (int r = 0; r < 4; ++r) {
        float* sb = sout + (size_t)(b0 + r) * (OC * OD) + o * OD + h * 8;
#pragma unroll
        for (int qq = 0; qq < 2; ++qq) {
            atomicAdd(sb + qq * 4 + 0, acc[r][qq].x * sc);
            atomicAdd(sb + qq * 4 + 1, acc[r][qq].y * sc);
            atomicAdd(sb + qq * 4 + 2, acc[r][qq].z * sc);
            atomicAdd(sb + qq * 4 + 3, acc[r][qq].w * sc);
        }
    }
}

// squash over d for each (b,o) row; optionally add vprev (to build v0+v1).
__global__ void squash_k(const float* __restrict__ s, const float* __restrict__ vprev,
                         float* __restrict__ vout)
{
    const int row = blockIdx.x * blockDim.x + threadIdx.x;   // 0..4095 = b*32+o
    if (row >= 128 * 32) return;
    const float4* s4 = (const float4*)s;
    float4 t[4];
    float sq = 0.f;
#pragma unroll
    for (int q = 0; q < 4; ++q) {
        t[q] = s4[row * 4 + q];
        sq += t[q].x * t[q].x + t[q].y * t[q].y + t[q].z * t[q].z + t[q].w * t[q].w;
    }
    const float f = sq / ((1.0f + sq) * sqrtf(sq + 1e-8f));
    float4* o4 = (float4*)vout;
    if (vprev) {
        const float4* p4 = (const float4*)vprev;
#pragma unroll
        for (int q = 0; q < 4; ++q) {
            float4 p = p4[row * 4 + q];
            float4 r;
            r.x = fmaf(t[q].x, f, p.x);
            r.y = fmaf(t[q].y, f, p.y);
            r.z = fmaf(t[q].z, f, p.z);
            r.w = fmaf(t[q].w, f, p.w);
            o4[row * 4 + q] = r;
        }
    } else {
#pragma unroll
        for (int q = 0; q < 4; ++q) {
            float4 r;
            r.x = t[q].x * f; r.y = t[q].y * f; r.z = t[q].z * f; r.w = t[q].w * f;
            o4[row * 4 + q] = r;
        }
    }
}

extern "C" void kernel_launch(void* const* d_in, const int* in_sizes, int n_in,
                              void* d_out, int out_size, void* d_ws, size_t ws_size,
                              hipStream_t stream)
{
    const float* x = (const float*)d_in[0];
    const float* W = (const float*)d_in[1];
    float* s  = (float*)d_ws;            // 65536 f32
    float* v0 = s + 65536;               // 65536 f32
    float* vs = v0 + 65536;              // 65536 f32 (v0 + v1)
    float* out = (float*)d_out;

    const size_t sbytes = (size_t)65536 * sizeof(float);

    // iter 0: uniform coupling 1/32
    hipMemsetAsync(s, 0, sbytes, stream);
    caps_pass<true><<<dim3(512), dim3(256), 0, stream>>>(x, W, nullptr, s);
    squash_k<<<dim3(16), dim3(256), 0, stream>>>(s, nullptr, v0);

    // iter 1: logits = dot(u_hat, v0)
    hipMemsetAsync(s, 0, sbytes, stream);
    caps_pass<false><<<dim3(512), dim3(256), 0, stream>>>(x, W, v0, s);
    squash_k<<<dim3(16), dim3(256), 0, stream>>>(s, v0, vs);   // vs = v0 + v1

    // iter 2: logits = dot(u_hat, v0+v1) = dot(u,v0) + dot(u,v1)
    hipMemsetAsync(s, 0, sbytes, stream);
    caps_pass<false><<<dim3(512), dim3(256), 0, stream>>>(x, W, vs, s);
    squash_k<<<dim3(16), dim3(256), 0, stream>>>(s, nullptr, out);
}

// Round 4
// 195.273 us; speedup vs baseline: 10.3879x; 2.9859x over previous
//
#include <hip/hip_runtime.h>

// CapsuleLayer dynamic routing on MI355X — round 4.
// x: [128, 2048, 8] f32, W: [2048, 32, 8, 16] f32, out v: [128, 32, 16] f32.
// Round-3 was atomic-bound (245 MB HBM write-through from 4.2M fp32 atomics).
// Fix: non-atomic per-block partials (16 MB ws) + fused reduce/squash kernel,
// x hoisted to LDS once, W double-buffered with counted vmcnt + raw s_barrier.

constexpr int NC = 2048;   // in_caps
constexpr int OC = 32;     // out_caps
constexpr int OD = 16;     // out_dim

typedef const __attribute__((address_space(1))) void* gas1_t;
typedef __attribute__((address_space(3))) void* las3_t;

__device__ __forceinline__ void gld16(const void* g, void* l) {
    __builtin_amdgcn_global_load_lds((gas1_t)g, (las3_t)l, 16, 0, 0);
}

#define MEMFENCE() asm volatile("" ::: "memory")
#define BAR() do { MEMFENCE(); __builtin_amdgcn_s_barrier(); MEMFENCE(); } while (0)

// grid = 512 blocks: bt(8) x nsup(64), XCD-swizzled (blocks sharing an nsup
// W-slice land on one XCD's L2). block = 256 threads = 4 waves.
// Block: b in [bt*16,+16), n in [nsup*32,+32), one n per chunk, 32 chunks.
// Wave w owns b0 = bt*16 + w*4 (R=4 reuse of every LDS W read).
// Lane: o = lane&31, d-half h = lane>>5 (d = h*8 + 0..7).
// W LDS layout per chunk: float4 unit o*32 + (c ^ (o&7)); staged with
// pre-swizzled global source, read back with the same XOR (conflict-bounded).
// ATOMIC=true is the small-ws fallback (round-3 style epilogue).
template<bool FIRST, bool ATOMIC>
__global__ __launch_bounds__(256)
__attribute__((amdgpu_waves_per_eu(2, 2)))
void caps_pass(const float* __restrict__ xg, const float* __restrict__ Wg,
               const float* __restrict__ vin, float* __restrict__ pout)
{
    __shared__ float4 Wl[2][1024];   // 32 KB: double-buffered, one n each
    __shared__ float4 xl[1024];      // 16 KB: [n(32)][b(16)][k(2)]

    const int tid  = threadIdx.x;
    const int bid  = blockIdx.x;
    const int nsup = (bid & 7) | ((bid >> 6) << 3);   // 0..63
    const int bt   = (bid >> 3) & 7;                  // 0..7
    const int w    = __builtin_amdgcn_readfirstlane(tid >> 6);
    const int lane = tid & 63;
    const int o    = lane & 31;
    const int h    = lane >> 5;
    const int sw   = o & 7;
    const int b0   = bt * 16 + w * 4;
    const int nbase = nsup * 32;

    const float4* Wg4 = (const float4*)Wg;
    const float4* xg4 = (const float4*)xg;

    float4 acc[4][2];
#pragma unroll
    for (int r = 0; r < 4; ++r)
#pragma unroll
        for (int qq = 0; qq < 2; ++qq) acc[r][qq] = make_float4(0.f, 0.f, 0.f, 0.f);

    float4 vr[4][2];
    if (!FIRST) {
        const float4* v4 = (const float4*)vin;
#pragma unroll
        for (int r = 0; r < 4; ++r)
#pragma unroll
            for (int qq = 0; qq < 2; ++qq)
                vr[r][qq] = v4[(size_t)(b0 + r) * 128 + o * 4 + h * 2 + qq];
    }

    // ---- prologue staging: x block-slice (4 gld16) + W chunk 0 (4 gld16) ----
#pragma unroll
    for (int j = 0; j < 4; ++j) {      // x: 1024 units [n][b][k]
        const int L = tid + 256 * j;
        const int n = L >> 5, bb = (L >> 1) & 15, k = L & 1;
        gld16(&xg4[(size_t)(bt * 16 + bb) * 4096 + (size_t)(nbase + n) * 2 + k], &xl[L]);
    }
#pragma unroll
    for (int j = 0; j < 4; ++j) {      // W chunk 0: 1024 units, pre-swizzled src
        const int L = tid + 256 * j;
        const int oo = L >> 5, cc = L & 31;
        gld16(&Wg4[(size_t)nbase * 1024 + oo * 32 + (cc ^ (oo & 7))], &Wl[0][L]);
    }

#pragma unroll 1
    for (int t = 0; t < 32; ++t) {
        // stage next W chunk into the other buffer (4 loads in flight)
        if (t < 31) {
#pragma unroll
            for (int j = 0; j < 4; ++j) {
                const int L = tid + 256 * j;
                const int oo = L >> 5, cc = L & 31;
                gld16(&Wg4[(size_t)(nbase + t + 1) * 1024 + oo * 32 + (cc ^ (oo & 7))],
                      &Wl[(t + 1) & 1][L]);
            }
            asm volatile("s_waitcnt vmcnt(4)" ::: "memory");  // chunk t (+x) done
        } else {
            asm volatile("s_waitcnt vmcnt(0)" ::: "memory");
        }
        BAR();   // all waves' chunk-t loads complete

        // ---- compute chunk t (n = nbase + t) ----
        float xr[4][8];
#pragma unroll
        for (int r = 0; r < 4; ++r) {
            const float4 xa = xl[t * 32 + (w * 4 + r) * 2 + 0];
            const float4 xb = xl[t * 32 + (w * 4 + r) * 2 + 1];
            xr[r][0] = xa.x; xr[r][1] = xa.y; xr[r][2] = xa.z; xr[r][3] = xa.w;
            xr[r][4] = xb.x; xr[r][5] = xb.y; xr[r][6] = xb.z; xr[r][7] = xb.w;
        }
        const float4* wrow = &Wl[t & 1][o * 32];

        if (FIRST) {
#pragma unroll
            for (int i = 0; i < 8; ++i)
#pragma unroll
                for (int qq = 0; qq < 2; ++qq) {
                    const float4 wv = wrow[(i * 4 + h * 2 + qq) ^ sw];
#pragma unroll
                    for (int r = 0; r < 4; ++r) {
                        acc[r][qq].x = fmaf(xr[r][i], wv.x, acc[r][qq].x);
                        acc[r][qq].y = fmaf(xr[r][i], wv.y, acc[r][qq].y);
                        acc[r][qq].z = fmaf(xr[r][i], wv.z, acc[r][qq].z);
                        acc[r][qq].w = fmaf(xr[r][i], wv.w, acc[r][qq].w);
                    }
                }
        } else {
            float4 u[4][2];
#pragma unroll
            for (int r = 0; r < 4; ++r)
#pragma unroll
                for (int qq = 0; qq < 2; ++qq) u[r][qq] = make_float4(0.f, 0.f, 0.f, 0.f);
#pragma unroll
            for (int i = 0; i < 8; ++i)
#pragma unroll
                for (int qq = 0; qq < 2; ++qq) {
                    const float4 wv = wrow[(i * 4 + h * 2 + qq) ^ sw];
#pragma unroll
                    for (int r = 0; r < 4; ++r) {
                        u[r][qq].x = fmaf(xr[r][i], wv.x, u[r][qq].x);
                        u[r][qq].y = fmaf(xr[r][i], wv.y, u[r][qq].y);
                        u[r][qq].z = fmaf(xr[r][i], wv.z, u[r][qq].z);
                        u[r][qq].w = fmaf(xr[r][i], wv.w, u[r][qq].w);
                    }
                }
#pragma unroll
            for (int r = 0; r < 4; ++r) {
                float tp = 0.f;
#pragma unroll
                for (int qq = 0; qq < 2; ++qq) {
                    tp = fmaf(u[r][qq].x, vr[r][qq].x, tp);
                    tp = fmaf(u[r][qq].y, vr[r][qq].y, tp);
                    tp = fmaf(u[r][qq].z, vr[r][qq].z, tp);
                    tp = fmaf(u[r][qq].w, vr[r][qq].w, tp);
                }
                const float tt = tp + __shfl_xor(tp, 32);
                // |t| small enough that exp without max-subtract is fp32-safe
                const float e = __expf(tt);
                float Z = e;
                Z += __shfl_xor(Z, 1);
                Z += __shfl_xor(Z, 2);
                Z += __shfl_xor(Z, 4);
                Z += __shfl_xor(Z, 8);
                Z += __shfl_xor(Z, 16);
                const float c = e / Z;
#pragma unroll
                for (int qq = 0; qq < 2; ++qq) {
                    acc[r][qq].x = fmaf(c, u[r][qq].x, acc[r][qq].x);
                    acc[r][qq].y = fmaf(c, u[r][qq].y, acc[r][qq].y);
                    acc[r][qq].z = fmaf(c, u[r][qq].z, acc[r][qq].z);
                    acc[r][qq].w = fmaf(c, u[r][qq].w, acc[r][qq].w);
                }
            }
        }
        BAR();   // all waves done reading Wl[t&1] before it is restaged
    }

    const float sc = FIRST ? (1.0f / 32.0f) : 1.0f;
    if (ATOMIC) {
        // fallback: atomic accumulate into s[b][o][d]
#pragma unroll
        for (int r = 0; r < 4; ++r) {
            float* sb = pout + (size_t)(b0 + r) * (OC * OD) + o * OD + h * 8;
#pragma unroll
            for (int qq = 0; qq < 2; ++qq) {
                atomicAdd(sb + qq * 4 + 0, acc[r][qq].x * sc);
                atomicAdd(sb + qq * 4 + 1, acc[r][qq].y * sc);
                atomicAdd(sb + qq * 4 + 2, acc[r][qq].z * sc);
                atomicAdd(sb + qq * 4 + 3, acc[r][qq].w * sc);
            }
        }
    } else {
        // partial store: P4[((nsup*128 + b)*4 + h*2+qq)*32 + o], coalesced
        float4* P4 = (float4*)pout;
#pragma unroll
        for (int r = 0; r < 4; ++r) {
            const size_t base = ((size_t)(nsup * 128 + b0 + r) * 4 + h * 2) * 32 + o;
#pragma unroll
            for (int qq = 0; qq < 2; ++qq) {
                float4 v;
                v.x = acc[r][qq].x * sc; v.y = acc[r][qq].y * sc;
                v.z = acc[r][qq].z * sc; v.w = acc[r][qq].w * sc;
                P4[base + (size_t)qq * 32] = v;
            }
        }
    }
}

// Fused reduce (over 64 nsup partials) + squash. grid 64 x 256.
// thread: b = blk*2 + (tid>>7), hq = (tid>>5)&3 (d-quad), o = tid&31.
// P unit = ns*16384 + blk*256 + tid  (fully coalesced).
__global__ void reduce_squash(const float* __restrict__ P, const float* __restrict__ vprev,
                              float* __restrict__ vout)
{
    __shared__ float sqb[256];
    const int tid = threadIdx.x;
    const int blk = blockIdx.x;
    const float4* P4 = (const float4*)P;

    float4 a = make_float4(0.f, 0.f, 0.f, 0.f);
#pragma unroll 4
    for (int ns = 0; ns < 64; ++ns) {
        const float4 p = P4[(size_t)ns * 16384 + blk * 256 + tid];
        a.x += p.x; a.y += p.y; a.z += p.z; a.w += p.w;
    }
    sqb[tid] = a.x * a.x + a.y * a.y + a.z * a.z + a.w * a.w;
    __syncthreads();
    const int base = tid & 0x9F;   // clear hq bits (5,6)
    const float sq = sqb[base] + sqb[base + 32] + sqb[base + 64] + sqb[base + 96];
    const float f = sq / ((1.0f + sq) * sqrtf(sq + 1e-8f));

    const int b  = blk * 2 + (tid >> 7);
    const int hq = (tid >> 5) & 3;
    const int o  = tid & 31;
    const size_t unit = (size_t)(b * 32 + o) * 4 + hq;
    float4 r;
    r.x = a.x * f; r.y = a.y * f; r.z = a.z * f; r.w = a.w * f;
    if (vprev) {
        const float4 p = ((const float4*)vprev)[unit];
        r.x += p.x; r.y += p.y; r.z += p.z; r.w += p.w;
    }
    ((float4*)vout)[unit] = r;
}

// atomic-path squash (round-3 style)
__global__ void squash_k(const float* __restrict__ s, const float* __restrict__ vprev,
                         float* __restrict__ vout)
{
    const int row = blockIdx.x * blockDim.x + threadIdx.x;
    if (row >= 128 * 32) return;
    const float4* s4 = (const float4*)s;
    float4 t[4];
    float sq = 0.f;
#pragma unroll
    for (int q = 0; q < 4; ++q) {
        t[q] = s4[row * 4 + q];
        sq += t[q].x * t[q].x + t[q].y * t[q].y + t[q].z * t[q].z + t[q].w * t[q].w;
    }
    const float f = sq / ((1.0f + sq) * sqrtf(sq + 1e-8f));
    float4* o4 = (float4*)vout;
#pragma unroll
    for (int q = 0; q < 4; ++q) {
        float4 r;
        r.x = t[q].x * f; r.y = t[q].y * f; r.z = t[q].z * f; r.w = t[q].w * f;
        if (vprev) {
            const float4 p = ((const float4*)vprev)[row * 4 + q];
            r.x += p.x; r.y += p.y; r.z += p.z; r.w += p.w;
        }
        o4[row * 4 + q] = r;
    }
}

extern "C" void kernel_launch(void* const* d_in, const int* in_sizes, int n_in,
                              void* d_out, int out_size, void* d_ws, size_t ws_size,
                              hipStream_t stream)
{
    const float* x = (const float*)d_in[0];
    const float* W = (const float*)d_in[1];
    float* out = (float*)d_out;

    const size_t P_FLOATS = (size_t)64 * 128 * 4 * 32 * 4;   // 4,194,304 floats = 16 MB
    const size_t NEED = (P_FLOATS + 2 * 65536) * sizeof(float);

    if (ws_size >= NEED) {
        float* P  = (float*)d_ws;
        float* v0 = P + P_FLOATS;
        float* vs = v0 + 65536;

        caps_pass<true, false><<<dim3(512), dim3(256), 0, stream>>>(x, W, nullptr, P);
        reduce_squash<<<dim3(64), dim3(256), 0, stream>>>(P, nullptr, v0);

        caps_pass<false, false><<<dim3(512), dim3(256), 0, stream>>>(x, W, v0, P);
        reduce_squash<<<dim3(64), dim3(256), 0, stream>>>(P, v0, vs);   // vs = v0 + v1

        caps_pass<false, false><<<dim3(512), dim3(256), 0, stream>>>(x, W, vs, P);
        reduce_squash<<<dim3(64), dim3(256), 0, stream>>>(P, nullptr, out);
    } else {
        // fallback: atomic epilogue (proven round-3 path)
        float* s  = (float*)d_ws;
        float* v0 = s + 65536;
        float* vs = v0 + 65536;
        const size_t sbytes = (size_t)65536 * sizeof(float);

        hipMemsetAsync(s, 0, sbytes, stream);
        caps_pass<true, true><<<dim3(512), dim3(256), 0, stream>>>(x, W, nullptr, s);
        squash_k<<<dim3(16), dim3(256), 0, stream>>>(s, nullptr, v0);

        hipMemsetAsync(s, 0, sbytes, stream);
        caps_pass<false, true><<<dim3(512), dim3(256), 0, stream>>>(x, W, v0, s);
        squash_k<<<dim3(16), dim3(256), 0, stream>>>(s, v0, vs);

        hipMemsetAsync(s, 0, sbytes, stream);
        caps_pass<false, true><<<dim3(512), dim3(256), 0, stream>>>(x, W, vs, s);
        squash_k<<<dim3(16), dim3(256), 0, stream>>>(s, nullptr, out);
    }
}